// Round 9
// baseline (224.215 us; speedup 1.0000x reference)
//
#include <hip/hip_runtime.h>

#define NN 100000
#define NE 1600000
#define NPB 128                       // nodes per coarse bucket (node>>7)
#define NBUCK ((NN + NPB - 1) / NPB)  // 782
#define NSB 512                       // scatter blocks
#define ESB (NE / NSB)                // 3125 edges per scatter block
#define PCAP 3072                     // LDS staging cap in place_deg (bucket avg ~2046)
// IN_C = HID_C = 64, OUT_C = 16

typedef __bf16 v8bf __attribute__((ext_vector_type(8)));
typedef float  v4f  __attribute__((ext_vector_type(4)));

union Frag { v8bf v; uint4 u; unsigned short s[8]; };

// fp32 -> bf16 (round-to-nearest-even), returns low 16 bits
__device__ inline unsigned f2bf(float f) {
    unsigned u = __float_as_uint(f);
    return (u + 0x7fffu + ((u >> 16) & 1u)) >> 16;
}

// 4 packed bf16 (uint2) -> float4
__device__ inline float4 bf4_to_f4(uint2 u) {
    float4 r;
    r.x = __uint_as_float(u.x << 16);
    r.y = __uint_as_float(u.x & 0xffff0000u);
    r.z = __uint_as_float(u.y << 16);
    r.w = __uint_as_float(u.y & 0xffff0000u);
    return r;
}

// ---------------- B: hist (512 blocks) ∥ wpack (2) ∥ counter init (1) --------
__global__ void hist_prep_kernel(const int* __restrict__ dst, int* __restrict__ histT,
                                 const float* __restrict__ W1, const float* __restrict__ W2,
                                 unsigned short* __restrict__ Wp1,
                                 unsigned short* __restrict__ Wp2,
                                 int* __restrict__ counter) {
    __shared__ int lhist[NBUCK];
    int t = threadIdx.x;
    int b = blockIdx.x;
    if (b >= NSB) {
        int w = b - NSB;
        if (w == 2) { if (t == 0) *counter = 0; return; }
        const float* W = w ? W2 : W1;
        unsigned short* Wp = w ? Wp2 : Wp1;
        for (int idx = t; idx < 4096; idx += 256) {
            int j = idx & 7;
            int n = (idx >> 3) & 15;
            int f = idx >> 7;          // 0..31
            int q = f & 3;
            int s = (f >> 2) & 1;
            int c = f >> 3;
            int k = 32 * s + 8 * q + j;
            int col = 16 * c + n;
            Wp[idx] = (unsigned short)f2bf(W[k * 64 + col]);
        }
        return;
    }
    for (int i = t; i < NBUCK; i += 256) lhist[i] = 0;
    __syncthreads();
    int start = b * ESB, end = start + ESB;
    for (int e = start + t; e < end; e += 256)
        atomicAdd(&lhist[dst[e] >> 7], 1);
    __syncthreads();
    for (int i = t; i < NBUCK; i += 256)
        histT[i * NSB + b] = lhist[i];   // transposed: bucket-major
}

// ---------------- C: per-bucket colscan + last-block bscan -------------------
__global__ void colscan_bscan_kernel(const int* __restrict__ histT, int* __restrict__ baseT,
                                     int* __restrict__ btot, int* __restrict__ bucket_start,
                                     int* __restrict__ counter) {
    __shared__ int sd[256];
    __shared__ int isLast;
    int k = blockIdx.x, t = threadIdx.x;
    const int* col = histT + k * NSB;
    int a0 = col[2 * t], a1 = col[2 * t + 1];
    int my = a0 + a1;
    sd[t] = my;
    __syncthreads();
    #pragma unroll
    for (int off = 1; off < 256; off <<= 1) {
        int v = (t >= off) ? sd[t - off] : 0;
        __syncthreads();
        sd[t] += v;
        __syncthreads();
    }
    int excl = sd[t] - my;
    baseT[k * NSB + 2 * t]     = excl;
    baseT[k * NSB + 2 * t + 1] = excl + a0;
    if (t == 255) atomicExch(&btot[k], sd[255]);     // device-scope publish
    __syncthreads();                                 // exch drained (vmcnt0 before barrier)
    if (t == 0) isLast = (atomicAdd(counter, 1) == NBUCK - 1);
    __syncthreads();
    if (!isLast) return;
    // ---- bscan, executed by the last-arriving block ----
    __threadfence();
    int base = t * 4;
    int d0 = (base + 0 < NBUCK) ? atomicAdd(&btot[base + 0], 0) : 0;
    int d1 = (base + 1 < NBUCK) ? atomicAdd(&btot[base + 1], 0) : 0;
    int d2 = (base + 2 < NBUCK) ? atomicAdd(&btot[base + 2], 0) : 0;
    int d3 = (base + 3 < NBUCK) ? atomicAdd(&btot[base + 3], 0) : 0;
    int m2 = d0 + d1 + d2 + d3;
    __syncthreads();           // sd reuse
    sd[t] = m2;
    __syncthreads();
    #pragma unroll
    for (int off = 1; off < 256; off <<= 1) {
        int v = (t >= off) ? sd[t - off] : 0;
        __syncthreads();
        sd[t] += v;
        __syncthreads();
    }
    int ex2 = sd[t] - m2;
    if (base + 0 < NBUCK) bucket_start[base + 0] = ex2;
    if (base + 1 < NBUCK) bucket_start[base + 1] = ex2 + d0;
    if (base + 2 < NBUCK) bucket_start[base + 2] = ex2 + d0 + d1;
    if (base + 3 < NBUCK) bucket_start[base + 3] = ex2 + d0 + d1 + d2;
    if (t == 255) bucket_start[NBUCK] = sd[255];   // == NE
}

// ---------------- D: stable bucket scatter, packed payload ----------------
// pack = (dst & 127) << 20 | src   (src < 2^20, loc < 2^7)
__global__ void scatter2_kernel(const int* __restrict__ src, const int* __restrict__ dst,
                                const int* __restrict__ baseT,
                                const int* __restrict__ bucket_start,
                                int* __restrict__ pairs) {
    __shared__ int lcur[NBUCK];
    int t = threadIdx.x, b = blockIdx.x;
    for (int i = t; i < NBUCK; i += 256)
        lcur[i] = bucket_start[i] + baseT[i * NSB + b];
    __syncthreads();
    int start = b * ESB, end = start + ESB;
    for (int e = start + t; e < end; e += 256) {
        int d = dst[e];
        int pos = atomicAdd(&lcur[d >> 7], 1);
        pairs[pos] = ((d & 127) << 20) | src[e];
    }
}

// ---------------- E: per-bucket deg/dinv/row_start + CSR placement + gemm1 ---
// Block k owns nodes [128k, 128k+128). After the LDS degree scan it has dinv
// locally, so its 4 waves run the 8 MFMA 16-node tiles of layer-1 gemm:
// hh1 = bf16((x @ W1) * dinv).
__global__ void place_deg_gemm1_kernel(const int* __restrict__ bucket_start,
                                       const int* __restrict__ pairs,
                                       const float* __restrict__ x,
                                       const unsigned short* __restrict__ Wp1,
                                       int* __restrict__ deg, float* __restrict__ dinv,
                                       int* __restrict__ row_start,
                                       int* __restrict__ sorted_src,
                                       unsigned* __restrict__ out /* hh1 bf16 rows */) {
    __shared__ int lp[PCAP];
    __shared__ int lcnt[NPB];
    __shared__ int loff[NPB];
    __shared__ int lpos[NPB];
    __shared__ int sd[NPB];
    __shared__ float ldinv[NPB];
    int k = blockIdx.x, t = threadIdx.x;
    int node0 = k * NPB;
    if (t < NPB) { lcnt[t] = 0; lpos[t] = 0; }
    __syncthreads();
    int bs = bucket_start[k], be = bucket_start[k + 1];
    int n = be - bs;
    for (int pos = t; pos < n; pos += 256) {
        int p = pairs[bs + pos];
        if (pos < PCAP) lp[pos] = p;
        atomicAdd(&lcnt[p >> 20], 1);
    }
    __syncthreads();
    int my = (t < NPB) ? lcnt[t] : 0;
    if (t < NPB) sd[t] = my;
    __syncthreads();
    #pragma unroll
    for (int off = 1; off < NPB; off <<= 1) {
        int v = (t < NPB && t >= off) ? sd[t - off] : 0;
        __syncthreads();
        if (t < NPB) sd[t] += v;
        __syncthreads();
    }
    if (t < NPB) {
        int excl = sd[t] - my;
        loff[t] = excl;
        float dv = rsqrtf((float)(my + 1));
        ldinv[t] = dv;
        int nd = node0 + t;
        if (nd < NN) {
            deg[nd] = my;
            dinv[nd] = dv;
            row_start[nd] = bs + excl;
        }
    }
    __syncthreads();
    for (int pos = t; pos < n; pos += 256) {
        int p = (pos < PCAP) ? lp[pos] : pairs[bs + pos];
        int loc = p >> 20;
        int off = atomicAdd(&lpos[loc], 1);
        sorted_src[bs + loff[loc] + off] = p & 0xFFFFF;
    }

    // ---- layer-1 gemm for this bucket's 128 nodes (2 tiles per wave) ----
    int lane = t & 63, wv = t >> 6;
    int m = lane & 15, quad = lane >> 4;
    Frag bfr[8];
    #pragma unroll
    for (int cs = 0; cs < 8; ++cs)
        bfr[cs].u = *(const uint4*)(Wp1 + ((cs * 4 + quad) * 16 + m) * 8);
    #pragma unroll
    for (int tt = 0; tt < 2; ++tt) {
        int tnode0 = node0 + (wv * 2 + tt) * 16;
        int node = tnode0 + m;
        int ln = (node < NN) ? node : NN - 1;
        Frag a[2];
        const float* xr = x + ln * 64 + quad * 8;
        #pragma unroll
        for (int s = 0; s < 2; ++s) {
            float4 f0 = *(const float4*)(xr + s * 32);
            float4 f1 = *(const float4*)(xr + s * 32 + 4);
            a[s].s[0] = (unsigned short)f2bf(f0.x);
            a[s].s[1] = (unsigned short)f2bf(f0.y);
            a[s].s[2] = (unsigned short)f2bf(f0.z);
            a[s].s[3] = (unsigned short)f2bf(f0.w);
            a[s].s[4] = (unsigned short)f2bf(f1.x);
            a[s].s[5] = (unsigned short)f2bf(f1.y);
            a[s].s[6] = (unsigned short)f2bf(f1.z);
            a[s].s[7] = (unsigned short)f2bf(f1.w);
        }
        v4f acc[4] = {};
        #pragma unroll
        for (int c = 0; c < 4; ++c) {
            acc[c] = __builtin_amdgcn_mfma_f32_16x16x32_bf16(a[0].v, bfr[c * 2 + 0].v, acc[c], 0, 0, 0);
            acc[c] = __builtin_amdgcn_mfma_f32_16x16x32_bf16(a[1].v, bfr[c * 2 + 1].v, acc[c], 0, 0, 0);
        }
        #pragma unroll
        for (int r = 0; r < 4; ++r) {
            int onode = tnode0 + quad * 4 + r;
            float di = ldinv[(onode - node0) & (NPB - 1)];
            #pragma unroll
            for (int c = 0; c < 4; ++c) {
                float v = acc[c][r] * di;
                float p = __shfl_xor(v, 1);
                if (!(lane & 1) && onode < NN) {
                    unsigned pk = f2bf(v) | (f2bf(p) << 16);
                    out[onode * 32 + c * 8 + (m >> 1)] = pk;
                }
            }
        }
    }
}

// ---------------- shared gather core: returns relu'd h float4 ----------------
__device__ inline float4 gather_row(const int* __restrict__ row_start,
                                    const int* __restrict__ deg,
                                    const int* __restrict__ sorted_src,
                                    const uint2* __restrict__ hb,
                                    const float* __restrict__ dinv,
                                    const float* __restrict__ b,
                                    int node, int q) {
    int e = row_start[node];
    int end = e + deg[node];
    float4 acc = bf4_to_f4(hb[node * 16 + q]);   // self-loop term
    while (e < end) {
        int take = min(end - e, 16);
        int sidx = (q < take) ? sorted_src[e + q] : 0;
        if (take == 16) {
            uint2 u[16];
            #pragma unroll
            for (int j = 0; j < 16; ++j) {
                int s = __shfl(sidx, j, 16);
                u[j] = hb[s * 16 + q];
            }
            #pragma unroll
            for (int j = 0; j < 16; ++j) {
                float4 v = bf4_to_f4(u[j]);
                acc.x += v.x; acc.y += v.y; acc.z += v.z; acc.w += v.w;
            }
        } else {
            int j = 0;
            for (; j + 4 <= take; j += 4) {
                int s0 = __shfl(sidx, j + 0, 16);
                int s1 = __shfl(sidx, j + 1, 16);
                int s2 = __shfl(sidx, j + 2, 16);
                int s3 = __shfl(sidx, j + 3, 16);
                uint2 u0 = hb[s0 * 16 + q];
                uint2 u1 = hb[s1 * 16 + q];
                uint2 u2 = hb[s2 * 16 + q];
                uint2 u3 = hb[s3 * 16 + q];
                float4 v0 = bf4_to_f4(u0), v1 = bf4_to_f4(u1);
                float4 v2 = bf4_to_f4(u2), v3 = bf4_to_f4(u3);
                acc.x += (v0.x + v1.x) + (v2.x + v3.x);
                acc.y += (v0.y + v1.y) + (v2.y + v3.y);
                acc.z += (v0.z + v1.z) + (v2.z + v3.z);
                acc.w += (v0.w + v1.w) + (v2.w + v3.w);
            }
            for (; j < take; ++j) {
                int s0 = __shfl(sidx, j, 16);
                float4 v0 = bf4_to_f4(hb[s0 * 16 + q]);
                acc.x += v0.x; acc.y += v0.y; acc.z += v0.z; acc.w += v0.w;
            }
        }
        e += take;
    }
    float di = dinv[node];
    float4 bb = *(const float4*)(b + q * 4);
    float4 r;
    r.x = fmaxf(fmaf(di, acc.x, bb.x), 0.f);
    r.y = fmaxf(fmaf(di, acc.y, bb.y), 0.f);
    r.z = fmaxf(fmaf(di, acc.z, bb.z), 0.f);
    r.w = fmaxf(fmaf(di, acc.w, bb.w), 0.f);
    return r;
}

// ---------------- F: layer-1 aggregate -> LDS -> layer-2 gemm (MFMA) ---------
__global__ void agg1_gemm2_kernel(const int* __restrict__ row_start,
                                  const int* __restrict__ deg,
                                  const int* __restrict__ sorted_src,
                                  const uint2* __restrict__ hb,    // hh1 bf16 rows
                                  const float* __restrict__ dinv,
                                  const float* __restrict__ b1,
                                  const unsigned short* __restrict__ Wp2,
                                  unsigned* __restrict__ out /* hh2 bf16 rows */) {
    __shared__ unsigned short hsl[64][72];   // 9216 B
    int t = threadIdx.x;
    int lane = t & 63, wv = t >> 6;
    int node0 = blockIdx.x * 64;
    int q = lane & 15;

    #pragma unroll
    for (int r4 = 0; r4 < 4; ++r4) {
        int nl = wv * 16 + r4 * 4 + (lane >> 4);
        int node = node0 + nl;
        int cn = (node < NN) ? node : NN - 1;
        float4 r = gather_row(row_start, deg, sorted_src, hb, dinv, b1, cn, q);
        uint2 pk;
        pk.x = f2bf(r.x) | (f2bf(r.y) << 16);
        pk.y = f2bf(r.z) | (f2bf(r.w) << 16);
        *(uint2*)&hsl[nl][q * 4] = pk;
    }
    __syncthreads();

    int m = lane & 15, quad = lane >> 4;
    Frag b[8];
    #pragma unroll
    for (int cs = 0; cs < 8; ++cs)
        b[cs].u = *(const uint4*)(Wp2 + ((cs * 4 + quad) * 16 + m) * 8);
    Frag a[2];
    #pragma unroll
    for (int s = 0; s < 2; ++s)
        a[s].u = *(const uint4*)&hsl[wv * 16 + m][s * 32 + quad * 8];

    v4f acc[4] = {};
    #pragma unroll
    for (int c = 0; c < 4; ++c) {
        acc[c] = __builtin_amdgcn_mfma_f32_16x16x32_bf16(a[0].v, b[c * 2 + 0].v, acc[c], 0, 0, 0);
        acc[c] = __builtin_amdgcn_mfma_f32_16x16x32_bf16(a[1].v, b[c * 2 + 1].v, acc[c], 0, 0, 0);
    }
    #pragma unroll
    for (int r = 0; r < 4; ++r) {
        int onode = node0 + wv * 16 + quad * 4 + r;
        float di = dinv[(onode < NN) ? onode : NN - 1];
        #pragma unroll
        for (int c = 0; c < 4; ++c) {
            float v = acc[c][r] * di;
            float p = __shfl_xor(v, 1);
            if (!(lane & 1) && onode < NN) {
                unsigned pk = f2bf(v) | (f2bf(p) << 16);
                out[onode * 32 + c * 8 + (m >> 1)] = pk;
            }
        }
    }
}

// ---------------- G: layer-2 aggregate fused with FC + log_softmax -----------
__global__ void aggregate2_final_kernel(const int* __restrict__ row_start,
                                        const int* __restrict__ deg,
                                        const int* __restrict__ sorted_src,
                                        const uint2* __restrict__ hb,
                                        const float* __restrict__ dinv,
                                        const float* __restrict__ b,
                                        const float* __restrict__ Wfc,
                                        const float* __restrict__ bfc,
                                        float* __restrict__ out) {
    __shared__ float Ws[64][16];   // 4 KB
    __shared__ float hs[16][68];   // padded
    int t = threadIdx.x;
    #pragma unroll
    for (int k = 0; k < 4; ++k)
        ((float*)Ws)[k * 256 + t] = Wfc[k * 256 + t];

    int node = blockIdx.x * 16 + (t >> 4);
    int q = t & 15;
    float4 r = gather_row(row_start, deg, sorted_src, hb, dinv, b, node, q);
    hs[t >> 4][q * 4 + 0] = r.x;
    hs[t >> 4][q * 4 + 1] = r.y;
    hs[t >> 4][q * 4 + 2] = r.z;
    hs[t >> 4][q * 4 + 3] = r.w;
    __syncthreads();

    int nl = t >> 4;
    int c  = t & 15;
    float acc = bfc[c];
    #pragma unroll
    for (int k = 0; k < 64; ++k)
        acc = fmaf(hs[nl][k], Ws[k][c], acc);
    float m = acc;
    #pragma unroll
    for (int off = 8; off; off >>= 1)
        m = fmaxf(m, __shfl_xor(m, off, 16));
    float ex = __expf(acc - m);
    float s = ex;
    #pragma unroll
    for (int off = 8; off; off >>= 1)
        s += __shfl_xor(s, off, 16);
    out[blockIdx.x * 256 + t] = acc - m - __logf(s);
}

extern "C" void kernel_launch(void* const* d_in, const int* in_sizes, int n_in,
                              void* d_out, int out_size, void* d_ws, size_t ws_size,
                              hipStream_t stream) {
    const float* x   = (const float*)d_in[0];
    const int*   ei  = (const int*)d_in[1];     // [2, E] int32
    const float* W1  = (const float*)d_in[2];
    const float* b1  = (const float*)d_in[3];
    const float* W2  = (const float*)d_in[4];
    const float* b2  = (const float*)d_in[5];
    const float* Wfc = (const float*)d_in[6];
    const float* bfc = (const float*)d_in[7];
    float* out = (float*)d_out;

    char* ws = (char*)d_ws;
    int*      deg          = (int*)(ws + 0);            // 400 KB
    float*    dinv         = (float*)(ws + 524288);     // 400 KB
    int*      row_start    = (int*)(ws + 1048576);      // 400 KB
    int*      btot         = (int*)(ws + 1572864);      // 3128 B
    int*      bucket_start = (int*)(ws + 1576960);      // 3132 B
    int*      counter      = (int*)(ws + 1580160);      // 4 B
    int*      histT        = (int*)(ws + 1581056);      // 1.6 MB (ends 3.18 MB)
    int*      baseT        = (int*)(ws + 3182592);      // 1.6 MB (ends 4.78 MB)
    int*      srt          = (int*)(ws + 4784128);      // 6.4 MB (ends 11.18 MB)
    unsigned* bufA         = (unsigned*)(ws + 11184128);// 12.8 MB bf16 hh1 (ends 23.98 MB)
    unsigned* bufC         = (unsigned*)(ws + 23984128);// 12.8 MB bf16 hh2 (ends 36.78 MB)
    int*      pairs        = (int*)(ws + 36784128);     // 6.4 MB (ends 43.18 MB)
    unsigned short* Wp1    = (unsigned short*)(ws + 43200000);  // 8 KB
    unsigned short* Wp2    = (unsigned short*)(ws + 43216384);  // 8 KB

    const int* src = ei;        // edge_index[0]
    const int* dst = ei + NE;   // edge_index[1]

    // B: histogram ∥ weight-pack ∥ ticket-counter init
    hist_prep_kernel<<<NSB + 3, 256, 0, stream>>>(dst, histT, W1, W2, Wp1, Wp2, counter);

    // C: per-bucket scan of block counts; last block scans bucket totals
    colscan_bscan_kernel<<<NBUCK, 256, 0, stream>>>(histT, baseT, btot, bucket_start, counter);

    // D: stable bucket scatter (packed payload, no global atomics)
    scatter2_kernel<<<NSB, 256, 0, stream>>>(src, dst, baseT, bucket_start, pairs);

    // E: deg/dinv/row_start + CSR placement + layer-1 gemm (MFMA), one launch
    place_deg_gemm1_kernel<<<NBUCK, 256, 0, stream>>>(bucket_start, pairs, x, Wp1,
        deg, dinv, row_start, srt, bufA);

    // F: layer-1 aggregate + layer-2 gemm (fused)
    agg1_gemm2_kernel<<<(NN + 63) / 64, 256, 0, stream>>>(row_start, deg, srt,
        (const uint2*)bufA, dinv, b1, Wp2, bufC);

    // G: layer-2 aggregate + FC + log_softmax (fused)
    aggregate2_final_kernel<<<NN * 16 / 256, 256, 0, stream>>>(row_start, deg, srt,
        (const uint2*)bufC, dinv, b2, Wfc, bfc, out);
}